// Round 7
// baseline (773.677 us; speedup 1.0000x reference)
//
#include <hip/hip_runtime.h>

#define EPS 1e-9f

constexpr int B_ = 8, N_ = 2048, M_ = 2048;
constexpr int THREADS = 256;
constexpr int WAVES = 4;
constexpr int RPW = 4;                       // rows per wave
constexpr int RPB = WAVES * RPW;             // 16 rows per block
constexpr int BPB = N_ / RPB;                // 128 blocks per batch
constexpr int GRID = B_ * BPB;               // 1024 blocks = exactly 4/CU

__global__ __launch_bounds__(THREADS) void init_kernel(float* rL, float* fb,
                                                       float* ss0, float* out) {
    int i = blockIdx.x * blockDim.x + threadIdx.x;
    if (i < B_ * N_) { rL[i] = 1.f; fb[i] = 0.f; ss0[i] = 0.f; }
    if (i < B_) out[i] = 0.f;
}

// One kernel per annealing step s: [phase2 of step s-1] + [phase1 of step s].
// LDS layout (exactly 40960 B -> 4 blocks/CU):
//   sx,sy,sz : raw xyz2                     (24 KB)
//   slg      : log2(g(s-1))                 ( 8 KB)  phase2 weight, folded
//   scw      : l2c*|p2|^2 + log2(rn(s))     ( 8 KB)  phase1 arg, folded
// phase2: e = exp2(l2p*d2 + lgg), d2 exact via diffs (sqrt needs it).
// phase1: arg = l2c*|p1|^2 + scw[m] - 2*l2c*dot  (dot-expansion; weight and
//         |p2|^2 pre-folded per column). Two-pass (rowsum then recompute) so
//         no per-element register storage -> no spills.
__global__ __launch_bounds__(THREADS, 4) void fused_step(
        const float* __restrict__ xyz1, const float* __restrict__ xyz2,
        float* __restrict__ rLb, float* __restrict__ fb,
        const float* __restrict__ rRp,   // rR(s-1) in   (unused if !has_p2)
        float* __restrict__ rRn_g,       // rR(s)  out   (designated block)
        const float* __restrict__ ssp_g, // ss(s-1) in   (unused if !has_p2)
        float* __restrict__ ssc_g,       // ss(s) atomic accumulate (pre-zeroed)
        float* __restrict__ ssz_g,       // ss(s+1) zeroed here for next kernel
        float* __restrict__ out,
        float l2p, float l2c, float m2l2c, int has_p2, int has_p1)
{
    __shared__ float smem[5 * M_];       // 40960 B exactly
    float* sx  = smem;
    float* sy  = smem + M_;
    float* sz  = smem + 2 * M_;
    float* slg = smem + 3 * M_;
    float* scw = smem + 4 * M_;
    float* ssl = smem;                   // 32 KB overlay after final barrier

    const int b   = blockIdx.x / BPB;
    const int blk = blockIdx.x % BPB;
    const int n0  = blk * RPB;
    const int tid = threadIdx.x;
    const bool designated = (blk == 0);

    // ---- staging ----
    const float* x2 = xyz2 + (size_t)b * M_ * 3;
    for (int m = tid; m < M_; m += THREADS) {
        const float x = x2[3*m], y = x2[3*m+1], z = x2[3*m+2];
        float g = 0.f, rn = 1.f;
        if (has_p2) {
            const float rr = rRp[b * M_ + m];
            const float s  = ssp_g[b * M_ + m];
            const float ratio = fminf(rr / (s + EPS), 1.f);
            g  = rr * ratio;
            rn = fmaxf(rr - s * ratio, 0.f);
        }
        sx[m] = x; sy[m] = y; sz[m] = z;
        slg[m] = __builtin_amdgcn_logf(g);                      // log2; log2(0)=-inf
        const float n2 = x*x + y*y + z*z;
        scw[m] = l2c * n2 + __builtin_amdgcn_logf(rn);
        if (designated) {
            if (has_p1) rRn_g[b * M_ + m] = rn;
            ssz_g[b * M_ + m] = 0.f;
        }
    }
    __syncthreads();

    const int wave = tid >> 6, lane = tid & 63;
    const int nw = n0 + wave * RPW;

    float xv[RPW], yv[RPW], zv[RPW], a1[RPW];
    #pragma unroll
    for (int r = 0; r < RPW; ++r) {
        const float* q = xyz1 + (size_t)(b * N_ + nw + r) * 3;
        xv[r] = q[0]; yv[r] = q[1]; zv[r] = q[2];
        a1[r] = l2c * (xv[r]*xv[r] + yv[r]*yv[r] + zv[r]*zv[r]);
    }

    // ---- phase2-part (level s-1): cost + rL update ----
    float rl_new[RPW];
    if (has_p2) {
        float accd[RPW], accc[RPW];
        #pragma unroll
        for (int r = 0; r < RPW; ++r) { accd[r] = 0.f; accc[r] = 0.f; }
        #pragma unroll
        for (int k = 0; k < 32; ++k) {
            const int m = lane + (k << 6);
            const float cx = sx[m], cy = sy[m], cz = sz[m], lg = slg[m];
            #pragma unroll
            for (int r = 0; r < RPW; ++r) {
                const float dx = xv[r]-cx, dy = yv[r]-cy, dz = zv[r]-cz;
                const float d2 = dx*dx + dy*dy + dz*dz;
                const float e = __builtin_amdgcn_exp2f(fmaf(l2p, d2, lg));
                accd[r] += e;
                accc[r] += e * __builtin_amdgcn_sqrtf(fmaxf(d2, 1e-20f));
            }
        }
        #pragma unroll
        for (int r = 0; r < RPW; ++r) {
            #pragma unroll
            for (int off = 32; off >= 1; off >>= 1) {
                accd[r] += __shfl_xor(accd[r], off, 64);
                accc[r] += __shfl_xor(accc[r], off, 64);
            }
        }
        float cw = 0.f;
        #pragma unroll
        for (int r = 0; r < RPW; ++r) {
            const int idx = b * N_ + nw + r;
            const float fo = fb[idx];
            const float rl = rLb[idx];
            rl_new[r] = fmaxf(rl - fo * accd[r], 0.f);
            cw += fo * accc[r];
        }
        if (lane == 0) atomicAdd(&out[b], cw);
    } else {
        #pragma unroll
        for (int r = 0; r < RPW; ++r) rl_new[r] = 1.f;
    }

    // ---- phase1-part (level s): rowsums -> f, column sums ----
    if (has_p1) {
        float p[RPW];
        #pragma unroll
        for (int r = 0; r < RPW; ++r) p[r] = 0.f;
        #pragma unroll
        for (int k = 0; k < 32; ++k) {
            const int m = lane + (k << 6);
            const float cx = sx[m], cy = sy[m], cz = sz[m], cw = scw[m];
            #pragma unroll
            for (int r = 0; r < RPW; ++r) {
                float dot = xv[r]*cx;
                dot = fmaf(yv[r], cy, dot);
                dot = fmaf(zv[r], cz, dot);
                p[r] += __builtin_amdgcn_exp2f(fmaf(m2l2c, dot, a1[r] + cw));
            }
        }
        #pragma unroll
        for (int r = 0; r < RPW; ++r) {
            #pragma unroll
            for (int off = 32; off >= 1; off >>= 1)
                p[r] += __shfl_xor(p[r], off, 64);
        }
        float fn[RPW];
        #pragma unroll
        for (int r = 0; r < RPW; ++r)
            fn[r] = rl_new[r] / (p[r] + EPS);
        if (lane == 0) {
            #pragma unroll
            for (int r = 0; r < RPW; ++r) {
                const int idx = b * N_ + nw + r;
                fb[idx]  = fn[r];
                rLb[idx] = rl_new[r];
            }
        }
        // pass B: recompute e, per-lane column sums
        float ssp[32];
        #pragma unroll
        for (int k = 0; k < 32; ++k) {
            const int m = lane + (k << 6);
            const float cx = sx[m], cy = sy[m], cz = sz[m], cw = scw[m];
            float s = 0.f;
            #pragma unroll
            for (int r = 0; r < RPW; ++r) {
                float dot = xv[r]*cx;
                dot = fmaf(yv[r], cy, dot);
                dot = fmaf(zv[r], cz, dot);
                const float e = __builtin_amdgcn_exp2f(fmaf(m2l2c, dot, a1[r] + cw));
                s = fmaf(e, fn[r], s);
            }
            ssp[k] = s;
        }
        __syncthreads();   // all LDS reads done; ssl overlay safe
        #pragma unroll
        for (int k = 0; k < 32; ++k)
            ssl[wave * M_ + lane + (k << 6)] = ssp[k];
        __syncthreads();
        for (int m = tid; m < M_; m += THREADS)
            atomicAdd(&ssc_g[b * M_ + m],
                      ssl[m] + ssl[M_ + m] + ssl[2*M_ + m] + ssl[3*M_ + m]);
    } else if (has_p2 && lane == 0) {
        #pragma unroll
        for (int r = 0; r < RPW; ++r)
            rLb[b * N_ + nw + r] = rl_new[r];
    }
}

extern "C" void kernel_launch(void* const* d_in, const int* in_sizes, int n_in,
                              void* d_out, int out_size, void* d_ws, size_t ws_size,
                              hipStream_t stream) {
    const float* xyz1 = (const float*)d_in[0];
    const float* xyz2 = (const float*)d_in[1];
    float* out = (float*)d_out;
    float* ws = (float*)d_ws;
    const int SZ = B_ * N_;          // == B_*M_ == 16384
    float* rL  = ws;
    float* fb  = ws + SZ;
    float* rRb[2] = { ws + 2*SZ, ws + 3*SZ };
    float* ssb[3] = { ws + 4*SZ, ws + 5*SZ, ws + 6*SZ };

    init_kernel<<<(SZ + THREADS - 1) / THREADS, THREADS, 0, stream>>>(
        rL, fb, ssb[0], out);

    constexpr float LOG2E = 1.4426950408889634f;
    static const float levels[10] = {
        -16384.f, -4096.f, -1024.f, -256.f, -64.f,
        -16.f, -4.f, -1.f, -0.25f, 0.f
    };
    // kernel s (s=0..10): phase2 of step s-1 (if s>0) + phase1 of step s (if s<10)
    for (int s = 0; s <= 10; ++s) {
        const int has_p2 = (s > 0);
        const int has_p1 = (s < 10);
        const float l2p = has_p2 ? levels[s-1] * LOG2E : 0.f;
        const float l2c = has_p1 ? levels[s]   * LOG2E : 0.f;
        fused_step<<<GRID, THREADS, 0, stream>>>(
            xyz1, xyz2, rL, fb,
            rRb[(s + 1) & 1],      // rR(s-1)
            rRb[s & 1],            // rR(s) out
            ssb[(s + 2) % 3],      // ss(s-1)
            ssb[s % 3],            // ss(s) accumulate (pre-zeroed)
            ssb[(s + 1) % 3],      // ss(s+1) zeroed for next kernel
            out, l2p, l2c, -2.f * l2c, has_p2, has_p1);
    }
}